// Round 5
// baseline (5725.217 us; speedup 1.0000x reference)
//
#include <hip/hip_runtime.h>
#include <stdint.h>

#define T_LEN 512
#define NB 64
#define STOPID 30

typedef unsigned short u16;
typedef unsigned int u32;
typedef short bf8 __attribute__((ext_vector_type(8)));
typedef float f32x4 __attribute__((ext_vector_type(4)));

__device__ __forceinline__ float bf2f(u16 v){ return __uint_as_float(((u32)v) << 16); }
__device__ __forceinline__ u16 f2bf(float f){
  u32 u = __float_as_uint(f);
  return (u16)((u + 0x7FFFu + ((u >> 16) & 1u)) >> 16);
}
__device__ __forceinline__ float sigm(float x){ return 1.0f/(1.0f + __expf(-x)); }
__device__ __forceinline__ float tanhfast(float x){ return 1.0f - 2.0f/(1.0f + __expf(2.0f*x)); }

// ---------------- K0: fp32 -> bf16 weight conversion (Whh + Wih, both dirs) ----------------
extern "C" __global__ __launch_bounds__(256) void k0_cvt(
    const float* __restrict__ whf, const float* __restrict__ whb,
    const float* __restrict__ wif, const float* __restrict__ wib,
    u16* __restrict__ whh_bf, u16* __restrict__ wih_bf)
{
  int i = blockIdx.x * 256 + threadIdx.x;   // grid 1024 -> 262144
  whh_bf[i]          = f2bf(whf[i]);
  whh_bf[262144 + i] = f2bf(whb[i]);
  wih_bf[i]          = f2bf(wif[i]);
  wih_bf[262144 + i] = f2bf(wib[i]);
}

// ---------------- K_init: zero h_init + barrier flags; compute lengths ----------------
extern "C" __global__ __launch_bounds__(256) void k_init(
    const int* __restrict__ mask, u32* __restrict__ h_init_u32,
    u32* __restrict__ cnt, int* __restrict__ lenv)
{
  int bid = blockIdx.x, tid = threadIdx.x;
  if (bid < 32) {
    h_init_u32[bid*256 + tid] = 0u;           // 8192 u32 = 32KB zeros (64x256 bf16 zeros)
  } else if (bid == 32) {
    cnt[tid] = 0u; cnt[256+tid] = 0u; cnt[512+tid] = 0u; cnt[768+tid] = 0u;
  } else {
    if (tid < 64) lenv[tid] = 0;
    __syncthreads();
    int r = tid >> 2, p = tid & 3;
    int s = 0;
    for (int k = 0; k < 128; ++k) s += mask[r*T_LEN + p*128 + k];
    atomicAdd(&lenv[r], s);
  }
}

// ---------------- KG: gather emb[inp] and convert to bf16, layout [t*64+b][256] ----------------
extern "C" __global__ __launch_bounds__(256) void kg_emb(
    const int* __restrict__ inp, const float* __restrict__ emb, u16* __restrict__ xemb)
{
  int r = blockIdx.x*2 + (threadIdx.x >> 7);    // 0..32767
  int col = (threadIdx.x & 127) * 2;
  int b = r & 63, t = r >> 6;
  int tok = inp[b*T_LEN + t];
  float2 v = *(const float2*)(emb + (size_t)tok*256 + col);
  u32 pk = ((u32)f2bf(v.x)) | (((u32)f2bf(v.y)) << 16);
  *(u32*)(xemb + (size_t)r*256 + col) = pk;
}

// ---------------- K1: xW[dir][t][gate][row] = bf16( xemb @ Wih^T + b ) via MFMA ----------------
extern "C" __global__ __launch_bounds__(256) void k1_proj(
    const u16* __restrict__ xemb, const u16* __restrict__ wih,
    const float* __restrict__ b_f, const float* __restrict__ b_b,
    u16* __restrict__ xW)
{
  int t  = blockIdx.x;
  int gb = blockIdx.y;              // 0..31
  int dir  = gb >> 4;
  int nblk = gb & 15;               // 64-gate block within dir
  int w    = threadIdx.x >> 6;      // wave id = M-tile (rows 16w..16w+16)
  int lane = threadIdx.x & 63;
  int lr = lane & 15, q = lane >> 4;

  bf8 af[8];
  #pragma unroll
  for (int kt = 0; kt < 8; ++kt)
    af[kt] = *(const bf8*)(xemb + ((size_t)t*64 + w*16 + lr)*256 + kt*32 + q*8);

  const u16* wbase = wih + (size_t)dir*262144 + (size_t)nblk*64*256;
  f32x4 acc[4];
  #pragma unroll
  for (int n = 0; n < 4; ++n) { acc[n][0]=0.f; acc[n][1]=0.f; acc[n][2]=0.f; acc[n][3]=0.f; }
  #pragma unroll
  for (int n = 0; n < 4; ++n) {
    #pragma unroll
    for (int kt = 0; kt < 8; ++kt) {
      bf8 b = *(const bf8*)(wbase + (size_t)(n*16 + lr)*256 + kt*32 + q*8);
      acc[n] = __builtin_amdgcn_mfma_f32_16x16x32_bf16(af[kt], b, acc[n], 0, 0, 0);
    }
  }

  const float* bias = dir ? b_b : b_f;
  u16* xp = xW + ((size_t)(dir*T_LEN + t)*1024 + nblk*64)*64;
  #pragma unroll
  for (int n = 0; n < 4; ++n) {
    float bv = bias[nblk*64 + n*16 + lr];
    ushort4 st;
    st.x = f2bf(acc[n][0] + bv);
    st.y = f2bf(acc[n][1] + bv);
    st.z = f2bf(acc[n][2] + bv);
    st.w = f2bf(acc[n][3] + bv);
    *(ushort4*)(xp + (size_t)(n*16 + lr)*64 + w*16 + q*4) = st;
  }
}

// ---------------- K2: LSTM recurrence, both directions folded per wave ----------------
// 8 blocks x 256 thr. Sync domain = 32-row group (rg): 16 waves over 4 blocks. Wave owns
// 16 chans x 4 gates x K=256 x BOTH dirs = 256 weight regs pinned to AGPRs ("+a" asm);
// working set stays in VGPRs (unified 512-reg budget at 1 wave/SIMD). Barrier: per-WAVE
// flag in one 64B line, no __syncthreads; every wave polls all 16 flags coalesced.
extern "C" __global__ __launch_bounds__(256, 1) void k2_lstm(
    const u16* __restrict__ whh, const u16* __restrict__ xW,
    const int* __restrict__ lenv, const u16* __restrict__ h_init,
    u16* __restrict__ h_out, u32* __restrict__ cnt)
{
  int blk = blockIdx.x;             // 0..7
  int rg  = blk >> 2;               // sync domain: 32-row group
  int bb  = blk & 3;
  int wv  = threadIdx.x >> 6;
  int lane = threadIdx.x & 63;
  int w  = bb*4 + wv;               // 0..15: chan slice
  int c0 = w*16;
  int lr = lane & 15, q = lane >> 4;
  int r0 = rg*32;

  // Whh B-fragments for BOTH dirs: 2 x 4 gates x 8 K-steps = 256 regs, pinned to AGPRs
  bf8 bw[2][4][8];
  #pragma unroll
  for (int d = 0; d < 2; ++d)
    #pragma unroll
    for (int g = 0; g < 4; ++g)
      #pragma unroll
      for (int kt = 0; kt < 8; ++kt)
        bw[d][g][kt] = *(const bf8*)(whh + (size_t)d*262144 + (size_t)(g*256 + c0 + lr)*256 + kt*32 + q*8);
  #pragma unroll
  for (int d = 0; d < 2; ++d)
    #pragma unroll
    for (int g = 0; g < 4; ++g) {
      asm volatile("" : "+a"(bw[d][g][0]), "+a"(bw[d][g][1]), "+a"(bw[d][g][2]), "+a"(bw[d][g][3]));
      asm volatile("" : "+a"(bw[d][g][4]), "+a"(bw[d][g][5]), "+a"(bw[d][g][6]), "+a"(bw[d][g][7]));
    }

  float cst[2][2][4];
  float hst[2][2][4];
  #pragma unroll
  for (int d = 0; d < 2; ++d)
    #pragma unroll
    for (int mt = 0; mt < 2; ++mt)
      #pragma unroll
      for (int J = 0; J < 4; ++J) { cst[d][mt][J] = 0.f; hst[d][mt][J] = 0.f; }
  int4 ln[2];
  ln[0] = *(const int4*)(lenv + r0 + q*4);
  ln[1] = *(const int4*)(lenv + r0 + 16 + q*4);

  u32* flg = cnt + rg*32;           // 16 dwords (one per wave), domains 128B apart

  int tf = 0, tb = T_LEN - 1;
  ushort4 xv[2][2][4];
  {
    #pragma unroll
    for (int d = 0; d < 2; ++d) {
      const u16* xp = xW + (size_t)(d*T_LEN + (d ? tb : tf))*1024*64;
      #pragma unroll
      for (int mt = 0; mt < 2; ++mt)
        #pragma unroll
        for (int g = 0; g < 4; ++g)
          xv[d][mt][g] = *(const ushort4*)(xp + (size_t)(g*256 + c0 + lr)*64 + r0 + mt*16 + q*4);
    }
  }
  const u16* hpf = h_init;
  const u16* hpb = h_init;

  for (int s = 0; s < T_LEN; ++s) {
    // A fragments for all (dir, mt) groups — issue all loads up front
    bf8 af[2][2][8];
    #pragma unroll
    for (int d = 0; d < 2; ++d) {
      const u16* hp = d ? hpb : hpf;
      #pragma unroll
      for (int mt = 0; mt < 2; ++mt)
        #pragma unroll
        for (int kt = 0; kt < 8; ++kt)
          af[d][mt][kt] = *(const bf8*)(hp + (size_t)(r0 + mt*16 + lr)*256 + kt*32 + q*8);
    }

    #pragma unroll
    for (int d = 0; d < 2; ++d) {
      int td = d ? tb : tf;
      u16* hop = h_out + (size_t)(d*T_LEN + td)*NB*256;
      #pragma unroll
      for (int mt = 0; mt < 2; ++mt) {
        f32x4 acc[4];
        #pragma unroll
        for (int g = 0; g < 4; ++g) { acc[g][0]=0.f; acc[g][1]=0.f; acc[g][2]=0.f; acc[g][3]=0.f; }
        #pragma unroll
        for (int kt = 0; kt < 8; ++kt)
          #pragma unroll
          for (int g = 0; g < 4; ++g)
            acc[g] = __builtin_amdgcn_mfma_f32_16x16x32_bf16(af[d][mt][kt], bw[d][g][kt], acc[g], 0, 0, 0);
        #pragma unroll
        for (int J = 0; J < 4; ++J) {
          float ip = acc[0][J] + bf2f(((const u16*)&xv[d][mt][0])[J]);
          float fp = acc[1][J] + bf2f(((const u16*)&xv[d][mt][1])[J]);
          float gp = acc[2][J] + bf2f(((const u16*)&xv[d][mt][2])[J]);
          float op = acc[3][J] + bf2f(((const u16*)&xv[d][mt][3])[J]);
          float cn = sigm(fp)*cst[d][mt][J] + sigm(ip)*tanhfast(gp);
          float hn = sigm(op)*tanhfast(cn);
          int lnj = ((const int*)&ln[mt])[J];
          bool mk = (td < lnj);
          cst[d][mt][J] = mk ? cn : cst[d][mt][J];
          hst[d][mt][J] = mk ? hn : hst[d][mt][J];
          __builtin_nontemporal_store(f2bf(hst[d][mt][J]),
              &hop[(size_t)(r0 + mt*16 + q*4 + J)*256 + c0 + lr]);
        }
      }
    }

    if (s < T_LEN-1) {
      __builtin_amdgcn_fence(__ATOMIC_RELEASE, "agent");   // drain my h stores
      if (lane == 0)
        __hip_atomic_store(&flg[w], (u32)(s+1), __ATOMIC_RELAXED, __HIP_MEMORY_SCOPE_AGENT);
      int tfn = s + 1, tbn = T_LEN - 2 - s;
      {  // prefetch next xW while waiting
        #pragma unroll
        for (int d = 0; d < 2; ++d) {
          const u16* xp = xW + (size_t)(d*T_LEN + (d ? tbn : tfn))*1024*64;
          #pragma unroll
          for (int mt = 0; mt < 2; ++mt)
            #pragma unroll
            for (int g = 0; g < 4; ++g)
              xv[d][mt][g] = *(const ushort4*)(xp + (size_t)(g*256 + c0 + lr)*64 + r0 + mt*16 + q*4);
        }
      }
      u32 tgt = (u32)(s+1);
      for (;;) {                    // all waves poll the 16-flag line (coalesced)
        u32 f = tgt;
        if (lane < 16)
          f = __hip_atomic_load(&flg[lane], __ATOMIC_RELAXED, __HIP_MEMORY_SCOPE_AGENT);
        if (__all((int)(f >= tgt))) break;
        __builtin_amdgcn_s_sleep(1);
      }
      __builtin_amdgcn_fence(__ATOMIC_ACQUIRE, "agent");   // invalidate stale cached h
      hpf = h_out + (size_t)tf*NB*256;
      hpb = h_out + (size_t)(T_LEN + tb)*NB*256;
      tf = tfn; tb = tbn;
    }
  }
}

// ---------------- K3: emissions em[t*64+b][32] = [h_f|h_b] @ W_tag^T + b_tag (fp32 out) ----------------
extern "C" __global__ __launch_bounds__(256, 2) void k3_emit(
    const u16* __restrict__ h_out, const float* __restrict__ W_tag,
    const float* __restrict__ b_tag, float* __restrict__ em)
{
  int wv = threadIdx.x >> 6, lane = threadIdx.x & 63;
  int lr = lane & 15, q = lane >> 4;
  size_t r0 = ((size_t)blockIdx.x*4 + wv) * 16;   // grid 512 -> 2048 row tiles (32768 rows)

  bf8 a[16];
  #pragma unroll
  for (int kt = 0; kt < 16; ++kt) {
    const u16* hp = h_out + (size_t)(kt>>3)*T_LEN*NB*256 + (r0 + lr)*256 + (kt&7)*32 + q*8;
    a[kt] = *(const bf8*)hp;
  }
  f32x4 acc[2];
  acc[0][0]=0.f;acc[0][1]=0.f;acc[0][2]=0.f;acc[0][3]=0.f; acc[1]=acc[0];
  #pragma unroll
  for (int n = 0; n < 2; ++n) {
    #pragma unroll
    for (int kt = 0; kt < 16; ++kt) {
      const float* wr = W_tag + (size_t)(n*16 + lr)*512 + kt*32 + q*8;
      bf8 bfr;
      #pragma unroll
      for (int e = 0; e < 8; ++e) bfr[e] = (short)f2bf(wr[e]);
      acc[n] = __builtin_amdgcn_mfma_f32_16x16x32_bf16(a[kt], bfr, acc[n], 0, 0, 0);
    }
  }
  #pragma unroll
  for (int n = 0; n < 2; ++n) {
    float bt = b_tag[n*16 + lr];
    #pragma unroll
    for (int J = 0; J < 4; ++J)
      em[(r0 + q*4 + J)*32 + n*16 + lr] = acc[n][J] + bt;
  }
}

// ---------------- K5: CRF forward scan + gold score; half-wave (32 lanes) per batch row ----------------
extern "C" __global__ __launch_bounds__(64) void k5_crf(
    const int* __restrict__ gold, const int* __restrict__ lenv,
    const float* __restrict__ em, const float* __restrict__ trans,
    float* __restrict__ out)
{
  __shared__ float trans_s[32][33];
  int tid = threadIdx.x;
  for (int i = tid; i < 1024; i += 64) trans_s[i>>5][i&31] = trans[i];
  __syncthreads();

  int half = tid >> 5;
  int j = tid & 31;                 // tag
  int b = blockIdx.x*2 + half;      // grid 32 -> b 0..63
  int len = lenv[b];
  float score = (j == STOPID) ? 0.f : -10000.f;
  float gscore = 0.f;
  int g_cur = gold[b*T_LEN];

  for (int t = 0; t < len; ++t) {
    float e = em[((size_t)t*64 + b)*32 + j];
    float m = -3.0e38f;
    #pragma unroll
    for (int p = 0; p < 32; ++p) {
      float sp = __shfl(score, p, 32);
      m = fmaxf(m, sp + trans_s[j][p]);
    }
    float se = 0.f;
    #pragma unroll
    for (int p = 0; p < 32; ++p) {
      float sp = __shfl(score, p, 32);
      se += __expf(sp + trans_s[j][p] - m);
    }
    score = e + m + __logf(se);
    if (t + 1 < T_LEN) {
      int g_next = gold[b*T_LEN + t + 1];
      float emg = __shfl(e, g_next, 32);
      gscore += emg + trans_s[g_next][g_cur];
      g_cur = g_next;
    }
  }
  float v = score + trans_s[STOPID][j];
  float m = v;
  #pragma unroll
  for (int off = 16; off; off >>= 1) m = fmaxf(m, __shfl_xor(m, off, 32));
  float se = __expf(v - m);
  #pragma unroll
  for (int off = 16; off; off >>= 1) se += __shfl_xor(se, off, 32);
  float Z = m + __logf(se);
  if (j == 0) {
    int g_last = gold[b*T_LEN + len - 1];
    out[b] = Z - (gscore + trans_s[STOPID][g_last]);
  }
}

extern "C" void kernel_launch(void* const* d_in, const int* in_sizes, int n_in,
                              void* d_out, int out_size, void* d_ws, size_t ws_size,
                              hipStream_t stream)
{
  const int*   inp   = (const int*)  d_in[0];
  const int*   gold  = (const int*)  d_in[1];
  const int*   mask  = (const int*)  d_in[2];
  const float* emb   = (const float*)d_in[3];
  const float* Wih_f = (const float*)d_in[4];
  const float* Whh_f = (const float*)d_in[5];
  const float* b_f   = (const float*)d_in[6];
  const float* Wih_b = (const float*)d_in[7];
  const float* Whh_b = (const float*)d_in[8];
  const float* b_b   = (const float*)d_in[9];
  const float* W_tag = (const float*)d_in[10];
  const float* b_tag = (const float*)d_in[11];
  const float* trans = (const float*)d_in[12];
  float* out = (float*)d_out;

  char* ws = (char*)d_ws;
  u16* whh_bf = (u16*)(ws + 0);                 // 1 MiB
  u16* wih_bf = (u16*)(ws + 1048576);           // 1 MiB
  u16* xW     = (u16*)(ws + 2097152);           // 128 MiB [dir][t][gate][row]   (lifetime: k1..k2)
  float* em   = (float*)(ws + 2097152);         // 4 MiB OVERLAY on xW           (lifetime: k3..k5)
  u16* h_outp = (u16*)(ws + 136314880);         // 32 MiB  [dir][t][row][256]    (lifetime: k2..k3)
  u16* xemb   = (u16*)(ws + 136314880);         // 16 MiB OVERLAY on h_out       (lifetime: kg..k1)
  u16* h_init = (u16*)(ws + 169869312);         // 32 KiB zeros
  u32* cntp   = (u32*)(ws + 169902080);         // 4 KiB barrier flags
  int* lenv   = (int*)(ws + 169906176);         // 256 B

  hipLaunchKernelGGL(k0_cvt,  dim3(1024),     dim3(256), 0, stream,
                     Whh_f, Whh_b, Wih_f, Wih_b, whh_bf, wih_bf);
  hipLaunchKernelGGL(k_init,  dim3(34),       dim3(256), 0, stream,
                     mask, (u32*)h_init, cntp, lenv);
  hipLaunchKernelGGL(kg_emb,  dim3(16384),    dim3(256), 0, stream, inp, emb, xemb);
  hipLaunchKernelGGL(k1_proj, dim3(512, 32),  dim3(256), 0, stream,
                     xemb, wih_bf, b_f, b_b, xW);
  hipLaunchKernelGGL(k2_lstm, dim3(8),        dim3(256), 0, stream,
                     whh_bf, xW, lenv, h_init, h_outp, cntp);
  hipLaunchKernelGGL(k3_emit, dim3(512),      dim3(256), 0, stream,
                     h_outp, W_tag, b_tag, em);
  hipLaunchKernelGGL(k5_crf,  dim3(32),       dim3(64),  0, stream,
                     gold, lenv, em, trans, out);
}

// Round 6
// 3386.015 us; speedup vs baseline: 1.6908x; 1.6908x over previous
//
#include <hip/hip_runtime.h>
#include <stdint.h>

#define T_LEN 512
#define NB 64
#define STOPID 30

typedef unsigned short u16;
typedef unsigned int u32;
typedef long long i64;
typedef short bf8 __attribute__((ext_vector_type(8)));
typedef float f32x4 __attribute__((ext_vector_type(4)));

__device__ __forceinline__ float bf2f(u16 v){ return __uint_as_float(((u32)v) << 16); }
__device__ __forceinline__ u16 f2bf(float f){
  u32 u = __float_as_uint(f);
  return (u16)((u + 0x7FFFu + ((u >> 16) & 1u)) >> 16);
}
__device__ __forceinline__ float sigm(float x){ return 1.0f/(1.0f + __expf(-x)); }
__device__ __forceinline__ float tanhfast(float x){ return 1.0f - 2.0f/(1.0f + __expf(2.0f*x)); }

// ---------------- K0: Wih -> bf16; Whh -> fp8 e4m3 (x4 scale, compensated by h*0.25) ----------------
extern "C" __global__ __launch_bounds__(256) void k0_cvt(
    const float* __restrict__ whf, const float* __restrict__ whb,
    const float* __restrict__ wif, const float* __restrict__ wib,
    u32* __restrict__ whh8, u16* __restrict__ wih_bf)
{
  int i = blockIdx.x * 256 + threadIdx.x;   // 0..262143
  wih_bf[i]          = f2bf(wif[i]);
  wih_bf[262144 + i] = f2bf(wib[i]);
  if (i < 131072) {
    const float* src = (i < 65536) ? (whf + (size_t)i*4) : (whb + (size_t)(i - 65536)*4);
    float4 v = *(const float4*)src;
    int hi = __builtin_amdgcn_cvt_pk_fp8_f32(v.z*4.f, v.w*4.f, 0, true);
    int pk = __builtin_amdgcn_cvt_pk_fp8_f32(v.x*4.f, v.y*4.f, hi, false);
    whh8[i] = (u32)pk;
  }
}

// ---------------- K_init: lengths per batch row (single block) ----------------
extern "C" __global__ __launch_bounds__(256) void k_init(
    const int* __restrict__ mask, int* __restrict__ lenv)
{
  int tid = threadIdx.x;
  if (tid < 64) lenv[tid] = 0;
  __syncthreads();
  int r = tid >> 2, p = tid & 3;
  int s = 0;
  for (int k = 0; k < 128; ++k) s += mask[r*T_LEN + p*128 + k];
  atomicAdd(&lenv[r], s);
}

// ---------------- KG: gather emb[inp] and convert to bf16, layout [t*64+b][256] ----------------
extern "C" __global__ __launch_bounds__(256) void kg_emb(
    const int* __restrict__ inp, const float* __restrict__ emb, u16* __restrict__ xemb)
{
  int r = blockIdx.x*2 + (threadIdx.x >> 7);    // 0..32767
  int col = (threadIdx.x & 127) * 2;
  int b = r & 63, t = r >> 6;
  int tok = inp[b*T_LEN + t];
  float2 v = *(const float2*)(emb + (size_t)tok*256 + col);
  u32 pk = ((u32)f2bf(v.x)) | (((u32)f2bf(v.y)) << 16);
  *(u32*)(xemb + (size_t)r*256 + col) = pk;
}

// ---------------- K1: xW[dir][t][gate][row] = bf16( xemb @ Wih^T + b ) via MFMA ----------------
extern "C" __global__ __launch_bounds__(256) void k1_proj(
    const u16* __restrict__ xemb, const u16* __restrict__ wih,
    const float* __restrict__ b_f, const float* __restrict__ b_b,
    u16* __restrict__ xW)
{
  int t  = blockIdx.x;
  int gb = blockIdx.y;              // 0..31
  int dir  = gb >> 4;
  int nblk = gb & 15;               // 64-gate block within dir
  int w    = threadIdx.x >> 6;      // wave id = M-tile (rows 16w..16w+16)
  int lane = threadIdx.x & 63;
  int lr = lane & 15, q = lane >> 4;

  bf8 af[8];
  #pragma unroll
  for (int kt = 0; kt < 8; ++kt)
    af[kt] = *(const bf8*)(xemb + ((size_t)t*64 + w*16 + lr)*256 + kt*32 + q*8);

  const u16* wbase = wih + (size_t)dir*262144 + (size_t)nblk*64*256;
  f32x4 acc[4];
  #pragma unroll
  for (int n = 0; n < 4; ++n) { acc[n][0]=0.f; acc[n][1]=0.f; acc[n][2]=0.f; acc[n][3]=0.f; }
  #pragma unroll
  for (int n = 0; n < 4; ++n) {
    #pragma unroll
    for (int kt = 0; kt < 8; ++kt) {
      bf8 b = *(const bf8*)(wbase + (size_t)(n*16 + lr)*256 + kt*32 + q*8);
      acc[n] = __builtin_amdgcn_mfma_f32_16x16x32_bf16(af[kt], b, acc[n], 0, 0, 0);
    }
  }

  const float* bias = dir ? b_b : b_f;
  u16* xp = xW + ((size_t)(dir*T_LEN + t)*1024 + nblk*64)*64;
  #pragma unroll
  for (int n = 0; n < 4; ++n) {
    float bv = bias[nblk*64 + n*16 + lr];
    ushort4 st;
    st.x = f2bf(acc[n][0] + bv);
    st.y = f2bf(acc[n][1] + bv);
    st.z = f2bf(acc[n][2] + bv);
    st.w = f2bf(acc[n][3] + bv);
    *(ushort4*)(xp + (size_t)(n*16 + lr)*64 + w*16 + q*4) = st;
  }
}

// ---------------- K2: LSTM recurrence, ZERO cross-block communication ----------------
// Block = (dir, 16-row group): 8 blocks x 512 thr (8 waves, 2/SIMD, 256-VGPR budget).
// Each block computes all 1024 gates for its 16 rows. Whh in fp8 e4m3 (x4; h scaled 0.25)
// register-resident: wave owns 32 chans x 4 gates x K=256 = 64 i64 frags = 128 VGPRs.
// h exchanged via LDS fp8 double buffer; ONE __syncthreads per step; no fences/atomics.
extern "C" __global__ __launch_bounds__(512, 2) void k2_lstm(
    const u32* __restrict__ whh8, const u16* __restrict__ xW,
    const int* __restrict__ lenv, u16* __restrict__ h_out)
{
  __shared__ __align__(16) unsigned char hb[2][16*264];

  int blk = blockIdx.x;             // 0..7
  int dir = blk >> 2;
  int rg  = blk & 3;
  int r0  = rg * 16;
  int w   = threadIdx.x >> 6;       // 0..7: chan slice (32 chans)
  int lane = threadIdx.x & 63;
  int lr = lane & 15, q = lane >> 4;
  int cw = w * 32;

  for (int i = threadIdx.x; i < 1056; i += 512)     // zero both h buffers (h(0)=0)
    ((unsigned long long*)hb)[i] = 0ull;

  // fp8 weight fragments: 4 gates x 2 chan-subtiles x 8 K-frags (128 VGPRs), pinned
  i64 bw[4][2][8];
  const unsigned char* wb = (const unsigned char*)whh8 + (size_t)dir*262144;
  #pragma unroll
  for (int g = 0; g < 4; ++g)
    #pragma unroll
    for (int s2 = 0; s2 < 2; ++s2)
      #pragma unroll
      for (int kt = 0; kt < 8; ++kt)
        bw[g][s2][kt] = *(const i64*)(wb + (size_t)(g*256 + cw + 16*s2 + lr)*256 + kt*32 + q*8);
  #pragma unroll
  for (int g = 0; g < 4; ++g)
    #pragma unroll
    for (int s2 = 0; s2 < 2; ++s2) {
      asm volatile("" : "+v"(bw[g][s2][0]), "+v"(bw[g][s2][1]), "+v"(bw[g][s2][2]), "+v"(bw[g][s2][3]));
      asm volatile("" : "+v"(bw[g][s2][4]), "+v"(bw[g][s2][5]), "+v"(bw[g][s2][6]), "+v"(bw[g][s2][7]));
    }

  float cst[2][4] = {{0.f,0.f,0.f,0.f},{0.f,0.f,0.f,0.f}};
  float hst[2][4] = {{0.f,0.f,0.f,0.f},{0.f,0.f,0.f,0.f}};
  int4 ln = *(const int4*)(lenv + r0 + q*4);

  int t0 = dir ? (T_LEN-1) : 0;
  ushort4 xv[4][2], xn[4][2];
  {
    const u16* xp = xW + (size_t)(dir*T_LEN + t0)*65536;
    #pragma unroll
    for (int g = 0; g < 4; ++g)
      #pragma unroll
      for (int s2 = 0; s2 < 2; ++s2)
        xv[g][s2] = *(const ushort4*)(xp + (size_t)(g*256 + cw + 16*s2 + lr)*64 + r0 + q*4);
  }
  __syncthreads();

  for (int s = 0; s < T_LEN; ++s) {
    int t = dir ? (T_LEN-1-s) : s;
    const unsigned char* hr = hb[s & 1];
    i64 af[8];
    #pragma unroll
    for (int kt = 0; kt < 8; ++kt)
      af[kt] = *(const i64*)(hr + lr*264 + kt*32 + q*8);

    if (s < T_LEN-1) {              // prefetch next xW under the MFMAs
      int tn = dir ? (T_LEN-2-s) : (s+1);
      const u16* xp = xW + (size_t)(dir*T_LEN + tn)*65536;
      #pragma unroll
      for (int g = 0; g < 4; ++g)
        #pragma unroll
        for (int s2 = 0; s2 < 2; ++s2)
          xn[g][s2] = *(const ushort4*)(xp + (size_t)(g*256 + cw + 16*s2 + lr)*64 + r0 + q*4);
    }

    unsigned char* hw = hb[(s+1) & 1];
    u16* ho = h_out + ((size_t)(dir*T_LEN + t)*NB + r0)*256;

    #pragma unroll
    for (int s2 = 0; s2 < 2; ++s2) {
      f32x4 acc[4];
      #pragma unroll
      for (int g = 0; g < 4; ++g) { acc[g][0]=0.f; acc[g][1]=0.f; acc[g][2]=0.f; acc[g][3]=0.f; }
      #pragma unroll
      for (int kt = 0; kt < 8; ++kt)
        #pragma unroll
        for (int g = 0; g < 4; ++g)
          acc[g] = __builtin_amdgcn_mfma_f32_16x16x32_fp8_fp8(af[kt], bw[g][s2][kt], acc[g], 0, 0, 0);
      #pragma unroll
      for (int J = 0; J < 4; ++J) {
        float ip = acc[0][J] + bf2f(((const u16*)&xv[0][s2])[J]);
        float fp = acc[1][J] + bf2f(((const u16*)&xv[1][s2])[J]);
        float gp = acc[2][J] + bf2f(((const u16*)&xv[2][s2])[J]);
        float op = acc[3][J] + bf2f(((const u16*)&xv[3][s2])[J]);
        float cn = sigm(fp)*cst[s2][J] + sigm(ip)*tanhfast(gp);
        float hn = sigm(op)*tanhfast(cn);
        int lnj = ((const int*)&ln)[J];
        bool mk = (t < lnj);
        cst[s2][J] = mk ? cn : cst[s2][J];
        hst[s2][J] = mk ? hn : hst[s2][J];
        int rl = q*4 + J;
        int ch = cw + 16*s2 + lr;
        u32 pk = (u32)__builtin_amdgcn_cvt_pk_fp8_f32(hst[s2][J]*0.25f, 0.0f, 0, false);
        hw[rl*264 + ch] = (unsigned char)(pk & 0xFFu);
        ho[(size_t)rl*256 + ch] = f2bf(hst[s2][J]);
      }
    }

    #pragma unroll
    for (int g = 0; g < 4; ++g)
      #pragma unroll
      for (int s2 = 0; s2 < 2; ++s2)
        xv[g][s2] = xn[g][s2];
    __syncthreads();
  }
}

// ---------------- K3: emissions em[t*64+b][32] = [h_f|h_b] @ W_tag^T + b_tag (fp32 out) ----------------
extern "C" __global__ __launch_bounds__(256, 2) void k3_emit(
    const u16* __restrict__ h_out, const float* __restrict__ W_tag,
    const float* __restrict__ b_tag, float* __restrict__ em)
{
  int wv = threadIdx.x >> 6, lane = threadIdx.x & 63;
  int lr = lane & 15, q = lane >> 4;
  size_t r0 = ((size_t)blockIdx.x*4 + wv) * 16;   // grid 512 -> 2048 row tiles (32768 rows)

  bf8 a[16];
  #pragma unroll
  for (int kt = 0; kt < 16; ++kt) {
    const u16* hp = h_out + (size_t)(kt>>3)*T_LEN*NB*256 + (r0 + lr)*256 + (kt&7)*32 + q*8;
    a[kt] = *(const bf8*)hp;
  }
  f32x4 acc[2];
  acc[0][0]=0.f;acc[0][1]=0.f;acc[0][2]=0.f;acc[0][3]=0.f; acc[1]=acc[0];
  #pragma unroll
  for (int n = 0; n < 2; ++n) {
    #pragma unroll
    for (int kt = 0; kt < 16; ++kt) {
      const float* wr = W_tag + (size_t)(n*16 + lr)*512 + kt*32 + q*8;
      bf8 bfr;
      #pragma unroll
      for (int e = 0; e < 8; ++e) bfr[e] = (short)f2bf(wr[e]);
      acc[n] = __builtin_amdgcn_mfma_f32_16x16x32_bf16(a[kt], bfr, acc[n], 0, 0, 0);
    }
  }
  #pragma unroll
  for (int n = 0; n < 2; ++n) {
    float bt = b_tag[n*16 + lr];
    #pragma unroll
    for (int J = 0; J < 4; ++J)
      em[(r0 + q*4 + J)*32 + n*16 + lr] = acc[n][J] + bt;
  }
}

// ---------------- K5: CRF forward scan + gold score; half-wave (32 lanes) per batch row ----------------
extern "C" __global__ __launch_bounds__(64) void k5_crf(
    const int* __restrict__ gold, const int* __restrict__ lenv,
    const float* __restrict__ em, const float* __restrict__ trans,
    float* __restrict__ out)
{
  __shared__ float trans_s[32][33];
  int tid = threadIdx.x;
  for (int i = tid; i < 1024; i += 64) trans_s[i>>5][i&31] = trans[i];
  __syncthreads();

  int half = tid >> 5;
  int j = tid & 31;                 // tag
  int b = blockIdx.x*2 + half;      // grid 32 -> b 0..63
  int len = lenv[b];
  float score = (j == STOPID) ? 0.f : -10000.f;
  float gscore = 0.f;
  int g_cur = gold[b*T_LEN];

  for (int t = 0; t < len; ++t) {
    float e = em[((size_t)t*64 + b)*32 + j];
    float m = -3.0e38f;
    #pragma unroll
    for (int p = 0; p < 32; ++p) {
      float sp = __shfl(score, p, 32);
      m = fmaxf(m, sp + trans_s[j][p]);
    }
    float se = 0.f;
    #pragma unroll
    for (int p = 0; p < 32; ++p) {
      float sp = __shfl(score, p, 32);
      se += __expf(sp + trans_s[j][p] - m);
    }
    score = e + m + __logf(se);
    if (t + 1 < T_LEN) {
      int g_next = gold[b*T_LEN + t + 1];
      float emg = __shfl(e, g_next, 32);
      gscore += emg + trans_s[g_next][g_cur];
      g_cur = g_next;
    }
  }
  float v = score + trans_s[STOPID][j];
  float m = v;
  #pragma unroll
  for (int off = 16; off; off >>= 1) m = fmaxf(m, __shfl_xor(m, off, 32));
  float se = __expf(v - m);
  #pragma unroll
  for (int off = 16; off; off >>= 1) se += __shfl_xor(se, off, 32);
  float Z = m + __logf(se);
  if (j == 0) {
    int g_last = gold[b*T_LEN + len - 1];
    out[b] = Z - (gscore + trans_s[STOPID][g_last]);
  }
}

extern "C" void kernel_launch(void* const* d_in, const int* in_sizes, int n_in,
                              void* d_out, int out_size, void* d_ws, size_t ws_size,
                              hipStream_t stream)
{
  const int*   inp   = (const int*)  d_in[0];
  const int*   gold  = (const int*)  d_in[1];
  const int*   mask  = (const int*)  d_in[2];
  const float* emb   = (const float*)d_in[3];
  const float* Wih_f = (const float*)d_in[4];
  const float* Whh_f = (const float*)d_in[5];
  const float* b_f   = (const float*)d_in[6];
  const float* Wih_b = (const float*)d_in[7];
  const float* Whh_b = (const float*)d_in[8];
  const float* b_b   = (const float*)d_in[9];
  const float* W_tag = (const float*)d_in[10];
  const float* b_tag = (const float*)d_in[11];
  const float* trans = (const float*)d_in[12];
  float* out = (float*)d_out;

  char* ws = (char*)d_ws;
  u32* whh8   = (u32*)(ws + 0);                 // 512 KiB fp8 Whh (both dirs)
  u16* wih_bf = (u16*)(ws + 1048576);           // 1 MiB bf16 Wih
  u16* xW     = (u16*)(ws + 2097152);           // 128 MiB [dir][t][gate][row]   (lifetime: k1..k2)
  float* em   = (float*)(ws + 2097152);         // 4 MiB OVERLAY on xW           (lifetime: k3..k5)
  u16* h_outp = (u16*)(ws + 136314880);         // 32 MiB  [dir][t][row][256]    (lifetime: k2..k3)
  u16* xemb   = (u16*)(ws + 136314880);         // 16 MiB OVERLAY on h_out       (lifetime: kg..k1)
  int* lenv   = (int*)(ws + 169869312);         // 256 B

  hipLaunchKernelGGL(k0_cvt,  dim3(1024),     dim3(256), 0, stream,
                     Whh_f, Whh_b, Wih_f, Wih_b, whh8, wih_bf);
  hipLaunchKernelGGL(k_init,  dim3(1),        dim3(256), 0, stream, mask, lenv);
  hipLaunchKernelGGL(kg_emb,  dim3(16384),    dim3(256), 0, stream, inp, emb, xemb);
  hipLaunchKernelGGL(k1_proj, dim3(512, 32),  dim3(256), 0, stream,
                     xemb, wih_bf, b_f, b_b, xW);
  hipLaunchKernelGGL(k2_lstm, dim3(8),        dim3(512), 0, stream,
                     whh8, xW, lenv, h_outp);
  hipLaunchKernelGGL(k3_emit, dim3(512),      dim3(256), 0, stream,
                     h_outp, W_tag, b_tag, em);
  hipLaunchKernelGGL(k5_crf,  dim3(32),       dim3(64),  0, stream,
                     gold, lenv, em, trans, out);
}

// Round 7
// 2633.031 us; speedup vs baseline: 2.1744x; 1.2860x over previous
//
#include <hip/hip_runtime.h>
#include <stdint.h>

#define T_LEN 512
#define NB 64
#define STOPID 30

typedef unsigned short u16;
typedef unsigned int u32;
typedef long long i64;
typedef short bf8 __attribute__((ext_vector_type(8)));
typedef float f32x4 __attribute__((ext_vector_type(4)));

__device__ __forceinline__ float bf2f(u16 v){ return __uint_as_float(((u32)v) << 16); }
__device__ __forceinline__ u16 f2bf(float f){
  u32 u = __float_as_uint(f);
  return (u16)((u + 0x7FFFu + ((u >> 16) & 1u)) >> 16);
}
__device__ __forceinline__ float sigm(float x){ return 1.0f/(1.0f + __expf(-x)); }
__device__ __forceinline__ float tanhfast(float x){ return 1.0f - 2.0f/(1.0f + __expf(2.0f*x)); }

// ---------------- K0: Wih -> bf16; Whh -> fp8 e4m3 (x4 scale, compensated by h*0.25) ----------------
extern "C" __global__ __launch_bounds__(256) void k0_cvt(
    const float* __restrict__ whf, const float* __restrict__ whb,
    const float* __restrict__ wif, const float* __restrict__ wib,
    u32* __restrict__ whh8, u16* __restrict__ wih_bf)
{
  int i = blockIdx.x * 256 + threadIdx.x;   // 0..262143
  wih_bf[i]          = f2bf(wif[i]);
  wih_bf[262144 + i] = f2bf(wib[i]);
  if (i < 131072) {
    const float* src = (i < 65536) ? (whf + (size_t)i*4) : (whb + (size_t)(i - 65536)*4);
    float4 v = *(const float4*)src;
    int hi = __builtin_amdgcn_cvt_pk_fp8_f32(v.z*4.f, v.w*4.f, 0, true);
    int pk = __builtin_amdgcn_cvt_pk_fp8_f32(v.x*4.f, v.y*4.f, hi, false);
    whh8[i] = (u32)pk;
  }
}

// ---------------- K_init: lengths per batch row (single block) ----------------
extern "C" __global__ __launch_bounds__(256) void k_init(
    const int* __restrict__ mask, int* __restrict__ lenv)
{
  int tid = threadIdx.x;
  if (tid < 64) lenv[tid] = 0;
  __syncthreads();
  int r = tid >> 2, p = tid & 3;
  int s = 0;
  for (int k = 0; k < 128; ++k) s += mask[r*T_LEN + p*128 + k];
  atomicAdd(&lenv[r], s);
}

// ---------------- KG: gather emb[inp] and convert to bf16, layout [t*64+b][256] ----------------
extern "C" __global__ __launch_bounds__(256) void kg_emb(
    const int* __restrict__ inp, const float* __restrict__ emb, u16* __restrict__ xemb)
{
  int r = blockIdx.x*2 + (threadIdx.x >> 7);    // 0..32767
  int col = (threadIdx.x & 127) * 2;
  int b = r & 63, t = r >> 6;
  int tok = inp[b*T_LEN + t];
  float2 v = *(const float2*)(emb + (size_t)tok*256 + col);
  u32 pk = ((u32)f2bf(v.x)) | (((u32)f2bf(v.y)) << 16);
  *(u32*)(xemb + (size_t)r*256 + col) = pk;
}

// ---------------- K1: xW[(dir*4+rg)][t][gate*16+row] = bf16( xemb @ Wih^T + b ) ----------------
// grid (64 t-chunks, 32): block does 8 timesteps with its 64-gate weight slice AGPR-resident.
// Output layout is per-(dir,row-group) contiguous so k2 streams 32KB/step with no over-fetch.
extern "C" __global__ __launch_bounds__(256, 1) void k1_proj(
    const u16* __restrict__ xemb, const u16* __restrict__ wih,
    const float* __restrict__ b_f, const float* __restrict__ b_b,
    u16* __restrict__ xW)
{
  int tc = blockIdx.x;              // t-chunk of 8
  int gb = blockIdx.y;              // 0..31
  int dir  = gb >> 4;
  int nblk = gb & 15;               // 64-gate block within dir
  int w    = threadIdx.x >> 6;      // wave id = row-group (rows 16w..16w+16)
  int lane = threadIdx.x & 63;
  int lr = lane & 15, q = lane >> 4;

  // weight fragments: 4 n-tiles x 8 K-frags = 128 regs, AGPR-pinned (loaded once / 8 t's)
  bf8 bw[4][8];
  const u16* wbase = wih + (size_t)dir*262144 + (size_t)nblk*64*256;
  #pragma unroll
  for (int n = 0; n < 4; ++n)
    #pragma unroll
    for (int kt = 0; kt < 8; ++kt)
      bw[n][kt] = *(const bf8*)(wbase + (size_t)(n*16 + lr)*256 + kt*32 + q*8);
  #pragma unroll
  for (int n = 0; n < 4; ++n) {
    asm volatile("" : "+a"(bw[n][0]), "+a"(bw[n][1]), "+a"(bw[n][2]), "+a"(bw[n][3]));
    asm volatile("" : "+a"(bw[n][4]), "+a"(bw[n][5]), "+a"(bw[n][6]), "+a"(bw[n][7]));
  }

  const float* bias = dir ? b_b : b_f;
  float bv[4];
  #pragma unroll
  for (int n = 0; n < 4; ++n) bv[n] = bias[nblk*64 + n*16 + lr];

  for (int ti = 0; ti < 8; ++ti) {
    int t = tc*8 + ti;
    bf8 af[8];
    #pragma unroll
    for (int kt = 0; kt < 8; ++kt)
      af[kt] = *(const bf8*)(xemb + ((size_t)t*64 + w*16 + lr)*256 + kt*32 + q*8);

    f32x4 acc[4];
    #pragma unroll
    for (int n = 0; n < 4; ++n) { acc[n][0]=0.f; acc[n][1]=0.f; acc[n][2]=0.f; acc[n][3]=0.f; }
    #pragma unroll
    for (int kt = 0; kt < 8; ++kt)
      #pragma unroll
      for (int n = 0; n < 4; ++n)
        acc[n] = __builtin_amdgcn_mfma_f32_16x16x32_bf16(af[kt], bw[n][kt], acc[n], 0, 0, 0);

    u16* xp = xW + ((size_t)(dir*4 + w)*T_LEN + t)*16384;
    #pragma unroll
    for (int n = 0; n < 4; ++n) {
      ushort4 st;
      st.x = f2bf(acc[n][0] + bv[n]);
      st.y = f2bf(acc[n][1] + bv[n]);
      st.z = f2bf(acc[n][2] + bv[n]);
      st.w = f2bf(acc[n][3] + bv[n]);
      *(ushort4*)(xp + (size_t)(nblk*64 + n*16 + lr)*16 + q*4) = st;
    }
  }
}

// ---------------- K2: LSTM recurrence, zero cross-block communication ----------------
// Block = (dir, 16-row group): 8 blocks x 512 thr (2 waves/SIMD, 256-reg unified budget).
// Whh fp8 e4m3 register-resident in AGPRs (128 AGPR/wave, "+a" pin). h in LDS fp8 double
// buffer, ONE __syncthreads/step. xW slice for t+1 prefetched after epilogue (xv dead),
// giving a full step (~1500 cyc) of latency cover with no extra registers.
extern "C" __global__ __launch_bounds__(512, 2) void k2_lstm(
    const u32* __restrict__ whh8, const u16* __restrict__ xW,
    const int* __restrict__ lenv, u16* __restrict__ h_out)
{
  __shared__ __align__(16) unsigned char hb[2][16*264];

  int blk = blockIdx.x;             // 0..7
  int dir = blk >> 2;
  int rg  = blk & 3;
  int r0  = rg * 16;
  int w   = threadIdx.x >> 6;       // 0..7: chan slice (32 chans)
  int lane = threadIdx.x & 63;
  int lr = lane & 15, q = lane >> 4;
  int cw = w * 32;

  for (int i = threadIdx.x; i < 1056; i += 512)     // zero both h buffers (h(0)=0)
    ((unsigned long long*)hb)[i] = 0ull;

  // fp8 weight fragments: 4 gates x 2 chan-subtiles x 8 K-frags = 128 AGPRs, pinned
  i64 bw[4][2][8];
  const unsigned char* wb = (const unsigned char*)whh8 + (size_t)dir*262144;
  #pragma unroll
  for (int g = 0; g < 4; ++g)
    #pragma unroll
    for (int s2 = 0; s2 < 2; ++s2)
      #pragma unroll
      for (int kt = 0; kt < 8; ++kt)
        bw[g][s2][kt] = *(const i64*)(wb + (size_t)(g*256 + cw + 16*s2 + lr)*256 + kt*32 + q*8);
  #pragma unroll
  for (int g = 0; g < 4; ++g)
    #pragma unroll
    for (int s2 = 0; s2 < 2; ++s2) {
      asm volatile("" : "+a"(bw[g][s2][0]), "+a"(bw[g][s2][1]), "+a"(bw[g][s2][2]), "+a"(bw[g][s2][3]));
      asm volatile("" : "+a"(bw[g][s2][4]), "+a"(bw[g][s2][5]), "+a"(bw[g][s2][6]), "+a"(bw[g][s2][7]));
    }

  float cst[2][4] = {{0.f,0.f,0.f,0.f},{0.f,0.f,0.f,0.f}};
  float hst[2][4] = {{0.f,0.f,0.f,0.f},{0.f,0.f,0.f,0.f}};
  int4 ln = *(const int4*)(lenv + r0 + q*4);

  const u16* xbase = xW + (size_t)(dir*4 + rg)*T_LEN*16384;
  int t0 = dir ? (T_LEN-1) : 0;
  ushort4 xv[4][2];
  {
    const u16* xp = xbase + (size_t)t0*16384;
    #pragma unroll
    for (int g = 0; g < 4; ++g)
      #pragma unroll
      for (int s2 = 0; s2 < 2; ++s2)
        xv[g][s2] = *(const ushort4*)(xp + (size_t)(g*256 + cw + 16*s2 + lr)*16 + q*4);
  }
  __syncthreads();

  for (int s = 0; s < T_LEN; ++s) {
    int t = dir ? (T_LEN-1-s) : s;
    const unsigned char* hr = hb[s & 1];
    i64 af[8];
    #pragma unroll
    for (int kt = 0; kt < 8; ++kt)
      af[kt] = *(const i64*)(hr + lr*264 + kt*32 + q*8);

    unsigned char* hw = hb[(s+1) & 1];
    u16* ho = h_out + ((size_t)(dir*T_LEN + t)*NB + r0)*256;

    #pragma unroll
    for (int s2 = 0; s2 < 2; ++s2) {
      f32x4 acc[4];
      #pragma unroll
      for (int g = 0; g < 4; ++g) { acc[g][0]=0.f; acc[g][1]=0.f; acc[g][2]=0.f; acc[g][3]=0.f; }
      #pragma unroll
      for (int kt = 0; kt < 8; ++kt)
        #pragma unroll
        for (int g = 0; g < 4; ++g)
          acc[g] = __builtin_amdgcn_mfma_f32_16x16x32_fp8_fp8(af[kt], bw[g][s2][kt], acc[g], 0, 0, 0);
      #pragma unroll
      for (int J = 0; J < 4; ++J) {
        float ip = acc[0][J] + bf2f(((const u16*)&xv[0][s2])[J]);
        float fp = acc[1][J] + bf2f(((const u16*)&xv[1][s2])[J]);
        float gp = acc[2][J] + bf2f(((const u16*)&xv[2][s2])[J]);
        float op = acc[3][J] + bf2f(((const u16*)&xv[3][s2])[J]);
        float cn = sigm(fp)*cst[s2][J] + sigm(ip)*tanhfast(gp);
        float hn = sigm(op)*tanhfast(cn);
        int lnj = ((const int*)&ln)[J];
        bool mk = (t < lnj);
        cst[s2][J] = mk ? cn : cst[s2][J];
        hst[s2][J] = mk ? hn : hst[s2][J];
        int rl = q*4 + J;
        int ch = cw + 16*s2 + lr;
        u32 pk = (u32)__builtin_amdgcn_cvt_pk_fp8_f32(hst[s2][J]*0.25f, 0.0f, 0, false);
        hw[rl*264 + ch] = (unsigned char)(pk & 0xFFu);
        ho[(size_t)rl*256 + ch] = f2bf(hst[s2][J]);
      }
    }

    if (s < T_LEN-1) {              // prefetch next xW slice; xv is dead here. Latency is
      int tn = dir ? (T_LEN-2-s) : (s+1);   // covered by LDS write + sync + af + MFMAs.
      const u16* xp = xbase + (size_t)tn*16384;
      #pragma unroll
      for (int g = 0; g < 4; ++g)
        #pragma unroll
        for (int s2 = 0; s2 < 2; ++s2)
          xv[g][s2] = *(const ushort4*)(xp + (size_t)(g*256 + cw + 16*s2 + lr)*16 + q*4);
    }
    __syncthreads();
  }
}

// ---------------- K3: emissions em[t*64+b][32] = [h_f|h_b] @ W_tag^T + b_tag (fp32 out) ----------------
extern "C" __global__ __launch_bounds__(256, 2) void k3_emit(
    const u16* __restrict__ h_out, const float* __restrict__ W_tag,
    const float* __restrict__ b_tag, float* __restrict__ em)
{
  int wv = threadIdx.x >> 6, lane = threadIdx.x & 63;
  int lr = lane & 15, q = lane >> 4;
  size_t r0 = ((size_t)blockIdx.x*4 + wv) * 16;   // grid 512 -> 2048 row tiles (32768 rows)

  bf8 a[16];
  #pragma unroll
  for (int kt = 0; kt < 16; ++kt) {
    const u16* hp = h_out + (size_t)(kt>>3)*T_LEN*NB*256 + (r0 + lr)*256 + (kt&7)*32 + q*8;
    a[kt] = *(const bf8*)hp;
  }
  f32x4 acc[2];
  acc[0][0]=0.f;acc[0][1]=0.f;acc[0][2]=0.f;acc[0][3]=0.f; acc[1]=acc[0];
  #pragma unroll
  for (int n = 0; n < 2; ++n) {
    #pragma unroll
    for (int kt = 0; kt < 16; ++kt) {
      const float* wr = W_tag + (size_t)(n*16 + lr)*512 + kt*32 + q*8;
      bf8 bfr;
      #pragma unroll
      for (int e = 0; e < 8; ++e) bfr[e] = (short)f2bf(wr[e]);
      acc[n] = __builtin_amdgcn_mfma_f32_16x16x32_bf16(a[kt], bfr, acc[n], 0, 0, 0);
    }
  }
  #pragma unroll
  for (int n = 0; n < 2; ++n) {
    float bt = b_tag[n*16 + lr];
    #pragma unroll
    for (int J = 0; J < 4; ++J)
      em[(r0 + q*4 + J)*32 + n*16 + lr] = acc[n][J] + bt;
  }
}

// ---------------- K5: CRF forward scan + gold score; half-wave (32 lanes) per batch row ----------------
extern "C" __global__ __launch_bounds__(64) void k5_crf(
    const int* __restrict__ gold, const int* __restrict__ lenv,
    const float* __restrict__ em, const float* __restrict__ trans,
    float* __restrict__ out)
{
  __shared__ float trans_s[32][33];
  int tid = threadIdx.x;
  for (int i = tid; i < 1024; i += 64) trans_s[i>>5][i&31] = trans[i];
  __syncthreads();

  int half = tid >> 5;
  int j = tid & 31;                 // tag
  int b = blockIdx.x*2 + half;      // grid 32 -> b 0..63
  int len = lenv[b];
  float score = (j == STOPID) ? 0.f : -10000.f;
  float gscore = 0.f;
  int g_cur = gold[b*T_LEN];

  float e = em[(size_t)b*32 + j];   // t=0 emission (len >= 256 always)
  for (int t = 0; t < len; ++t) {
    float en = (t+1 < len) ? em[((size_t)(t+1)*64 + b)*32 + j] : 0.f;  // prefetch off critical path
    float m = -3.0e38f;
    #pragma unroll
    for (int p = 0; p < 32; ++p) {
      float sp = __shfl(score, p, 32);
      m = fmaxf(m, sp + trans_s[j][p]);
    }
    float se = 0.f;
    #pragma unroll
    for (int p = 0; p < 32; ++p) {
      float sp = __shfl(score, p, 32);
      se += __expf(sp + trans_s[j][p] - m);
    }
    score = e + m + __logf(se);
    if (t + 1 < T_LEN) {
      int g_next = gold[b*T_LEN + t + 1];
      float emg = __shfl(e, g_next, 32);
      gscore += emg + trans_s[g_next][g_cur];
      g_cur = g_next;
    }
    e = en;
  }
  float v = score + trans_s[STOPID][j];
  float m = v;
  #pragma unroll
  for (int off = 16; off; off >>= 1) m = fmaxf(m, __shfl_xor(m, off, 32));
  float se = __expf(v - m);
  #pragma unroll
  for (int off = 16; off; off >>= 1) se += __shfl_xor(se, off, 32);
  float Z = m + __logf(se);
  if (j == 0) {
    int g_last = gold[b*T_LEN + len - 1];
    out[b] = Z - (gscore + trans_s[STOPID][g_last]);
  }
}

extern "C" void kernel_launch(void* const* d_in, const int* in_sizes, int n_in,
                              void* d_out, int out_size, void* d_ws, size_t ws_size,
                              hipStream_t stream)
{
  const int*   inp   = (const int*)  d_in[0];
  const int*   gold  = (const int*)  d_in[1];
  const int*   mask  = (const int*)  d_in[2];
  const float* emb   = (const float*)d_in[3];
  const float* Wih_f = (const float*)d_in[4];
  const float* Whh_f = (const float*)d_in[5];
  const float* b_f   = (const float*)d_in[6];
  const float* Wih_b = (const float*)d_in[7];
  const float* Whh_b = (const float*)d_in[8];
  const float* b_b   = (const float*)d_in[9];
  const float* W_tag = (const float*)d_in[10];
  const float* b_tag = (const float*)d_in[11];
  const float* trans = (const float*)d_in[12];
  float* out = (float*)d_out;

  char* ws = (char*)d_ws;
  u32* whh8   = (u32*)(ws + 0);                 // 512 KiB fp8 Whh (both dirs)
  u16* wih_bf = (u16*)(ws + 1048576);           // 1 MiB bf16 Wih
  u16* xW     = (u16*)(ws + 2097152);           // 128 MiB [(dir,rg)][t][gate*16+row]  (k1..k2)
  float* em   = (float*)(ws + 2097152);         // 4 MiB OVERLAY on xW                 (k3..k5)
  u16* h_outp = (u16*)(ws + 136314880);         // 32 MiB  [dir][t][row][256]          (k2..k3)
  u16* xemb   = (u16*)(ws + 136314880);         // 16 MiB OVERLAY on h_out             (kg..k1)
  int* lenv   = (int*)(ws + 169869312);         // 256 B

  hipLaunchKernelGGL(k0_cvt,  dim3(1024),     dim3(256), 0, stream,
                     Whh_f, Whh_b, Wih_f, Wih_b, whh8, wih_bf);
  hipLaunchKernelGGL(k_init,  dim3(1),        dim3(256), 0, stream, mask, lenv);
  hipLaunchKernelGGL(kg_emb,  dim3(16384),    dim3(256), 0, stream, inp, emb, xemb);
  hipLaunchKernelGGL(k1_proj, dim3(64, 32),   dim3(256), 0, stream,
                     xemb, wih_bf, b_f, b_b, xW);
  hipLaunchKernelGGL(k2_lstm, dim3(8),        dim3(512), 0, stream,
                     whh8, xW, lenv, h_outp);
  hipLaunchKernelGGL(k3_emit, dim3(512),      dim3(256), 0, stream,
                     h_outp, W_tag, b_tag, em);
  hipLaunchKernelGGL(k5_crf,  dim3(32),       dim3(64),  0, stream,
                     gold, lenv, em, trans, out);
}

// Round 8
// 2472.602 us; speedup vs baseline: 2.3155x; 1.0649x over previous
//
#include <hip/hip_runtime.h>
#include <stdint.h>

#define T_LEN 512
#define NB 64
#define STOPID 30

typedef unsigned short u16;
typedef unsigned int u32;
typedef long long i64;
typedef short bf8 __attribute__((ext_vector_type(8)));
typedef float f32x4 __attribute__((ext_vector_type(4)));

__device__ __forceinline__ float bf2f(u16 v){ return __uint_as_float(((u32)v) << 16); }
__device__ __forceinline__ u16 f2bf(float f){
  u32 u = __float_as_uint(f);
  return (u16)((u + 0x7FFFu + ((u >> 16) & 1u)) >> 16);
}
__device__ __forceinline__ float sigm(float x){ return 1.0f/(1.0f + __expf(-x)); }
__device__ __forceinline__ float tanhfast(float x){ return 1.0f - 2.0f/(1.0f + __expf(2.0f*x)); }

// ---------------- K0: Wih -> bf16; Whh -> fp8 e4m3 (x4 scale, compensated by h*0.25) ----------------
extern "C" __global__ __launch_bounds__(256) void k0_cvt(
    const float* __restrict__ whf, const float* __restrict__ whb,
    const float* __restrict__ wif, const float* __restrict__ wib,
    u32* __restrict__ whh8, u16* __restrict__ wih_bf)
{
  int i = blockIdx.x * 256 + threadIdx.x;   // 0..262143
  wih_bf[i]          = f2bf(wif[i]);
  wih_bf[262144 + i] = f2bf(wib[i]);
  if (i < 131072) {
    const float* src = (i < 65536) ? (whf + (size_t)i*4) : (whb + (size_t)(i - 65536)*4);
    float4 v = *(const float4*)src;
    int hi = __builtin_amdgcn_cvt_pk_fp8_f32(v.z*4.f, v.w*4.f, 0, true);
    int pk = __builtin_amdgcn_cvt_pk_fp8_f32(v.x*4.f, v.y*4.f, hi, false);
    whh8[i] = (u32)pk;
  }
}

// ---------------- K_init: lengths per batch row (single block) ----------------
extern "C" __global__ __launch_bounds__(256) void k_init(
    const int* __restrict__ mask, int* __restrict__ lenv)
{
  int tid = threadIdx.x;
  if (tid < 64) lenv[tid] = 0;
  __syncthreads();
  int r = tid >> 2, p = tid & 3;
  int s = 0;
  for (int k = 0; k < 128; ++k) s += mask[r*T_LEN + p*128 + k];
  atomicAdd(&lenv[r], s);
}

// ---------------- KG: gather emb[inp] and convert to bf16, layout [t*64+b][256] ----------------
extern "C" __global__ __launch_bounds__(256) void kg_emb(
    const int* __restrict__ inp, const float* __restrict__ emb, u16* __restrict__ xemb)
{
  int r = blockIdx.x*2 + (threadIdx.x >> 7);    // 0..32767
  int col = (threadIdx.x & 127) * 2;
  int b = r & 63, t = r >> 6;
  int tok = inp[b*T_LEN + t];
  float2 v = *(const float2*)(emb + (size_t)tok*256 + col);
  u32 pk = ((u32)f2bf(v.x)) | (((u32)f2bf(v.y)) << 16);
  *(u32*)(xemb + (size_t)r*256 + col) = pk;
}

// ---------------- K1: xW[(dir*4+rg)][t][row16][1024] = bf16( xemb @ Wih^T + b ) ----------------
// Swapped operands: A = Wih (M=gates, AGPR-resident), B = xemb (N=16 rows). Lane holds
// row=lane&15, gates q*4+J consecutive -> 8B coalesced stores into the row-major xW layout
// k2 wants. grid (64 t-chunks, 32): 8 timesteps per block, weights loaded once.
extern "C" __global__ __launch_bounds__(256, 1) void k1_proj(
    const u16* __restrict__ xemb, const u16* __restrict__ wih,
    const float* __restrict__ b_f, const float* __restrict__ b_b,
    u16* __restrict__ xW)
{
  int tc = blockIdx.x;              // t-chunk of 8
  int gb = blockIdx.y;              // 0..31
  int dir  = gb >> 4;
  int nblk = gb & 15;               // 64-gate block within dir
  int w    = threadIdx.x >> 6;      // wave id = row-group (rows 16w..16w+16)
  int lane = threadIdx.x & 63;
  int lr = lane & 15, q = lane >> 4;

  // A-operand weight fragments: 4 m-tiles x 8 K-frags = 128 regs, AGPR-pinned
  bf8 bw[4][8];
  const u16* wbase = wih + (size_t)dir*262144 + (size_t)nblk*64*256;
  #pragma unroll
  for (int n = 0; n < 4; ++n)
    #pragma unroll
    for (int kt = 0; kt < 8; ++kt)
      bw[n][kt] = *(const bf8*)(wbase + (size_t)(n*16 + lr)*256 + kt*32 + q*8);
  #pragma unroll
  for (int n = 0; n < 4; ++n) {
    asm volatile("" : "+a"(bw[n][0]), "+a"(bw[n][1]), "+a"(bw[n][2]), "+a"(bw[n][3]));
    asm volatile("" : "+a"(bw[n][4]), "+a"(bw[n][5]), "+a"(bw[n][6]), "+a"(bw[n][7]));
  }

  const float* bias = dir ? b_b : b_f;
  float4 bv[4];
  #pragma unroll
  for (int n = 0; n < 4; ++n) bv[n] = *(const float4*)(bias + nblk*64 + n*16 + q*4);

  for (int ti = 0; ti < 8; ++ti) {
    int t = tc*8 + ti;
    bf8 af[8];   // B-operand: xemb rows (n = lane&15)
    #pragma unroll
    for (int kt = 0; kt < 8; ++kt)
      af[kt] = *(const bf8*)(xemb + ((size_t)t*64 + w*16 + lr)*256 + kt*32 + q*8);

    f32x4 acc[4];
    #pragma unroll
    for (int n = 0; n < 4; ++n) { acc[n][0]=0.f; acc[n][1]=0.f; acc[n][2]=0.f; acc[n][3]=0.f; }
    #pragma unroll
    for (int kt = 0; kt < 8; ++kt)
      #pragma unroll
      for (int n = 0; n < 4; ++n)
        acc[n] = __builtin_amdgcn_mfma_f32_16x16x32_bf16(bw[n][kt], af[kt], acc[n], 0, 0, 0);

    // C: col = lane&15 = batch row, row(m) = gate n*16 + q*4 + J -> 8B store per n-tile
    u16* xp = xW + ((size_t)(dir*4 + w)*T_LEN + t)*16384 + (size_t)lr*1024;
    #pragma unroll
    for (int n = 0; n < 4; ++n) {
      ushort4 st;
      st.x = f2bf(acc[n][0] + bv[n].x);
      st.y = f2bf(acc[n][1] + bv[n].y);
      st.z = f2bf(acc[n][2] + bv[n].z);
      st.w = f2bf(acc[n][3] + bv[n].w);
      *(ushort4*)(xp + nblk*64 + n*16 + q*4) = st;
    }
  }
}

// ---------------- K2: LSTM recurrence, zero cross-block communication ----------------
// Block = (dir, 16-row group): 8 blocks x 512 thr (2 waves/SIMD). Whh fp8 AGPR-resident
// (128 accum/wave). Swapped operands: A=W (M=gates), B=h (N=rows); lane owns 1 row x 4
// consecutive chans per tile -> wide stores, scalar row mask. xW folded into MFMA C-init
// so xv dies at step start; prefetch for t+1 issues immediately after and is covered by
// MFMA+epilogue before the barrier's vmcnt(0) drain. ONE __syncthreads/step, no fences.
extern "C" __global__ __launch_bounds__(512, 2) void k2_lstm(
    const u32* __restrict__ whh8, const u16* __restrict__ xW,
    const int* __restrict__ lenv, u16* __restrict__ h_out)
{
  __shared__ __align__(16) unsigned char hb[2][16*264];

  int blk = blockIdx.x;             // 0..7
  int dir = blk >> 2;
  int rg  = blk & 3;
  int r0  = rg * 16;
  int w   = threadIdx.x >> 6;       // 0..7: chan slice (32 chans)
  int lane = threadIdx.x & 63;
  int lr = lane & 15, q = lane >> 4;
  int cw = w * 32;

  for (int i = threadIdx.x; i < 1056; i += 512)     // zero both h buffers (h(0)=0)
    ((unsigned long long*)hb)[i] = 0ull;

  // A-operand fp8 weight fragments: 4 gates x 2 chan-subtiles x 8 K-frags = 128 AGPRs
  i64 bw[4][2][8];
  const unsigned char* wb = (const unsigned char*)whh8 + (size_t)dir*262144;
  #pragma unroll
  for (int g = 0; g < 4; ++g)
    #pragma unroll
    for (int s2 = 0; s2 < 2; ++s2)
      #pragma unroll
      for (int kt = 0; kt < 8; ++kt)
        bw[g][s2][kt] = *(const i64*)(wb + (size_t)(g*256 + cw + 16*s2 + lr)*256 + kt*32 + q*8);
  #pragma unroll
  for (int g = 0; g < 4; ++g)
    #pragma unroll
    for (int s2 = 0; s2 < 2; ++s2) {
      asm volatile("" : "+a"(bw[g][s2][0]), "+a"(bw[g][s2][1]), "+a"(bw[g][s2][2]), "+a"(bw[g][s2][3]));
      asm volatile("" : "+a"(bw[g][s2][4]), "+a"(bw[g][s2][5]), "+a"(bw[g][s2][6]), "+a"(bw[g][s2][7]));
    }

  float cst[2][4] = {{0.f,0.f,0.f,0.f},{0.f,0.f,0.f,0.f}};
  float hst[2][4] = {{0.f,0.f,0.f,0.f},{0.f,0.f,0.f,0.f}};
  int lnr = lenv[r0 + lr];          // row mask is per-lane scalar now

  const u16* xbase = xW + (size_t)(dir*4 + rg)*T_LEN*16384 + (size_t)lr*1024;
  int t0 = dir ? (T_LEN-1) : 0;
  ushort4 xv[4][2];                 // [g][s2]: xW[t][row lr][g*256+cw+16*s2+q*4 ..+3]
  {
    const u16* xp = xbase + (size_t)t0*16384;
    #pragma unroll
    for (int g = 0; g < 4; ++g)
      #pragma unroll
      for (int s2 = 0; s2 < 2; ++s2)
        xv[g][s2] = *(const ushort4*)(xp + g*256 + cw + 16*s2 + q*4);
  }
  __syncthreads();

  for (int s = 0; s < T_LEN; ++s) {
    int t = dir ? (T_LEN-1-s) : s;
    const unsigned char* hr = hb[s & 1];
    i64 af[8];                      // B-operand: h rows (n = lane&15)
    #pragma unroll
    for (int kt = 0; kt < 8; ++kt)
      af[kt] = *(const i64*)(hr + lr*264 + kt*32 + q*8);

    // C-init = xW contribution; xv dead after this
    f32x4 acc[2][4];
    #pragma unroll
    for (int s2 = 0; s2 < 2; ++s2)
      #pragma unroll
      for (int g = 0; g < 4; ++g)
        #pragma unroll
        for (int J = 0; J < 4; ++J)
          acc[s2][g][J] = bf2f(((const u16*)&xv[g][s2])[J]);

    if (s < T_LEN-1) {              // prefetch next xW NOW — covered by MFMA+epilogue
      int tn = dir ? (T_LEN-2-s) : (s+1);
      const u16* xp = xbase + (size_t)tn*16384;
      #pragma unroll
      for (int g = 0; g < 4; ++g)
        #pragma unroll
        for (int s2 = 0; s2 < 2; ++s2)
          xv[g][s2] = *(const ushort4*)(xp + g*256 + cw + 16*s2 + q*4);
    }

    #pragma unroll
    for (int kt = 0; kt < 8; ++kt)
      #pragma unroll
      for (int s2 = 0; s2 < 2; ++s2)
        #pragma unroll
        for (int g = 0; g < 4; ++g)
          acc[s2][g] = __builtin_amdgcn_mfma_f32_16x16x32_fp8_fp8(bw[g][s2][kt], af[kt], acc[s2][g], 0, 0, 0);

    unsigned char* hw = hb[(s+1) & 1];
    u16* ho = h_out + ((size_t)(dir*T_LEN + t)*NB + r0 + lr)*256;
    bool mk = (t < lnr);
    #pragma unroll
    for (int s2 = 0; s2 < 2; ++s2) {
      ushort4 hv;
      #pragma unroll
      for (int J = 0; J < 4; ++J) {
        float ip = acc[s2][0][J];
        float fp = acc[s2][1][J];
        float gp = acc[s2][2][J];
        float op = acc[s2][3][J];
        float cn = sigm(fp)*cst[s2][J] + sigm(ip)*tanhfast(gp);
        float hn = sigm(op)*tanhfast(cn);
        cst[s2][J] = mk ? cn : cst[s2][J];
        hst[s2][J] = mk ? hn : hst[s2][J];
        ((u16*)&hv)[J] = f2bf(hst[s2][J]);
      }
      int lo = __builtin_amdgcn_cvt_pk_fp8_f32(hst[s2][0]*0.25f, hst[s2][1]*0.25f, 0, false);
      int pk = __builtin_amdgcn_cvt_pk_fp8_f32(hst[s2][2]*0.25f, hst[s2][3]*0.25f, lo, true);
      int ch = cw + 16*s2 + q*4;
      *(u32*)(hw + lr*264 + ch) = (u32)pk;       // 4B LDS write (fp8 x4)
      *(ushort4*)(ho + ch) = hv;                 // 8B global store (bf16 x4)
    }
    __syncthreads();
  }
}

// ---------------- K3: emissions em[t*64+b][32] = [h_f|h_b] @ W_tag^T + b_tag (fp32 out) ----------------
extern "C" __global__ __launch_bounds__(256, 2) void k3_emit(
    const u16* __restrict__ h_out, const float* __restrict__ W_tag,
    const float* __restrict__ b_tag, float* __restrict__ em)
{
  int wv = threadIdx.x >> 6, lane = threadIdx.x & 63;
  int lr = lane & 15, q = lane >> 4;
  size_t r0 = ((size_t)blockIdx.x*4 + wv) * 16;   // grid 512 -> 2048 row tiles (32768 rows)

  bf8 a[16];
  #pragma unroll
  for (int kt = 0; kt < 16; ++kt) {
    const u16* hp = h_out + (size_t)(kt>>3)*T_LEN*NB*256 + (r0 + lr)*256 + (kt&7)*32 + q*8;
    a[kt] = *(const bf8*)hp;
  }
  f32x4 acc[2];
  acc[0][0]=0.f;acc[0][1]=0.f;acc[0][2]=0.f;acc[0][3]=0.f; acc[1]=acc[0];
  #pragma unroll
  for (int n = 0; n < 2; ++n) {
    #pragma unroll
    for (int kt = 0; kt < 16; ++kt) {
      const float* wr = W_tag + (size_t)(n*16 + lr)*512 + kt*32 + q*8;
      bf8 bfr;
      #pragma unroll
      for (int e = 0; e < 8; ++e) bfr[e] = (short)f2bf(wr[e]);
      acc[n] = __builtin_amdgcn_mfma_f32_16x16x32_bf16(a[kt], bfr, acc[n], 0, 0, 0);
    }
  }
  #pragma unroll
  for (int n = 0; n < 2; ++n) {
    float bt = b_tag[n*16 + lr];
    #pragma unroll
    for (int J = 0; J < 4; ++J)
      em[(r0 + q*4 + J)*32 + n*16 + lr] = acc[n][J] + bt;
  }
}

// ---------------- K5: CRF forward scan + gold score; half-wave (32 lanes) per batch row ----------------
extern "C" __global__ __launch_bounds__(64) void k5_crf(
    const int* __restrict__ gold, const int* __restrict__ lenv,
    const float* __restrict__ em, const float* __restrict__ trans,
    float* __restrict__ out)
{
  __shared__ float trans_s[32][33];
  int tid = threadIdx.x;
  for (int i = tid; i < 1024; i += 64) trans_s[i>>5][i&31] = trans[i];
  __syncthreads();

  int half = tid >> 5;
  int j = tid & 31;                 // tag
  int b = blockIdx.x*2 + half;      // grid 32 -> b 0..63
  int len = lenv[b];
  float score = (j == STOPID) ? 0.f : -10000.f;
  float gscore = 0.f;
  int g_cur = gold[b*T_LEN];

  float e = em[(size_t)b*32 + j];   // t=0 emission (len >= 256 always)
  for (int t = 0; t < len; ++t) {
    float en = (t+1 < len) ? em[((size_t)(t+1)*64 + b)*32 + j] : 0.f;  // prefetch off critical path
    float m = -3.0e38f;
    #pragma unroll
    for (int p = 0; p < 32; ++p) {
      float sp = __shfl(score, p, 32);
      m = fmaxf(m, sp + trans_s[j][p]);
    }
    float se = 0.f;
    #pragma unroll
    for (int p = 0; p < 32; ++p) {
      float sp = __shfl(score, p, 32);
      se += __expf(sp + trans_s[j][p] - m);
    }
    score = e + m + __logf(se);
    if (t + 1 < T_LEN) {
      int g_next = gold[b*T_LEN + t + 1];
      float emg = __shfl(e, g_next, 32);
      gscore += emg + trans_s[g_next][g_cur];
      g_cur = g_next;
    }
    e = en;
  }
  float v = score + trans_s[STOPID][j];
  float m = v;
  #pragma unroll
  for (int off = 16; off; off >>= 1) m = fmaxf(m, __shfl_xor(m, off, 32));
  float se = __expf(v - m);
  #pragma unroll
  for (int off = 16; off; off >>= 1) se += __shfl_xor(se, off, 32);
  float Z = m + __logf(se);
  if (j == 0) {
    int g_last = gold[b*T_LEN + len - 1];
    out[b] = Z - (gscore + trans_s[STOPID][g_last]);
  }
}

extern "C" void kernel_launch(void* const* d_in, const int* in_sizes, int n_in,
                              void* d_out, int out_size, void* d_ws, size_t ws_size,
                              hipStream_t stream)
{
  const int*   inp   = (const int*)  d_in[0];
  const int*   gold  = (const int*)  d_in[1];
  const int*   mask  = (const int*)  d_in[2];
  const float* emb   = (const float*)d_in[3];
  const float* Wih_f = (const float*)d_in[4];
  const float* Whh_f = (const float*)d_in[5];
  const float* b_f   = (const float*)d_in[6];
  const float* Wih_b = (const float*)d_in[7];
  const float* Whh_b = (const float*)d_in[8];
  const float* b_b   = (const float*)d_in[9];
  const float* W_tag = (const float*)d_in[10];
  const float* b_tag = (const float*)d_in[11];
  const float* trans = (const float*)d_in[12];
  float* out = (float*)d_out;

  char* ws = (char*)d_ws;
  u32* whh8   = (u32*)(ws + 0);                 // 512 KiB fp8 Whh (both dirs)
  u16* wih_bf = (u16*)(ws + 1048576);           // 1 MiB bf16 Wih
  u16* xW     = (u16*)(ws + 2097152);           // 128 MiB [(dir,rg)][t][row16][1024]  (k1..k2)
  float* em   = (float*)(ws + 2097152);         // 4 MiB OVERLAY on xW                 (k3..k5)
  u16* h_outp = (u16*)(ws + 136314880);         // 32 MiB  [dir][t][row][256]          (k2..k3)
  u16* xemb   = (u16*)(ws + 136314880);         // 16 MiB OVERLAY on h_out             (kg..k1)
  int* lenv   = (int*)(ws + 169869312);         // 256 B

  hipLaunchKernelGGL(k0_cvt,  dim3(1024),     dim3(256), 0, stream,
                     Whh_f, Whh_b, Wih_f, Wih_b, whh8, wih_bf);
  hipLaunchKernelGGL(k_init,  dim3(1),        dim3(256), 0, stream, mask, lenv);
  hipLaunchKernelGGL(kg_emb,  dim3(16384),    dim3(256), 0, stream, inp, emb, xemb);
  hipLaunchKernelGGL(k1_proj, dim3(64, 32),   dim3(256), 0, stream,
                     xemb, wih_bf, b_f, b_b, xW);
  hipLaunchKernelGGL(k2_lstm, dim3(8),        dim3(512), 0, stream,
                     whh8, xW, lenv, h_outp);
  hipLaunchKernelGGL(k3_emit, dim3(512),      dim3(256), 0, stream,
                     h_outp, W_tag, b_tag, em);
  hipLaunchKernelGGL(k5_crf,  dim3(32),       dim3(64),  0, stream,
                     gold, lenv, em, trans, out);
}

// Round 9
// 1987.740 us; speedup vs baseline: 2.8803x; 1.2439x over previous
//
#include <hip/hip_runtime.h>
#include <stdint.h>

#define T_LEN 512
#define NB 64
#define STOPID 30

typedef unsigned short u16;
typedef unsigned int u32;
typedef long long i64;
typedef short bf8 __attribute__((ext_vector_type(8)));
typedef float f32x4 __attribute__((ext_vector_type(4)));

__device__ __forceinline__ float bf2f(u16 v){ return __uint_as_float(((u32)v) << 16); }
__device__ __forceinline__ u16 f2bf(float f){
  u32 u = __float_as_uint(f);
  return (u16)((u + 0x7FFFu + ((u >> 16) & 1u)) >> 16);
}
// fast sigmoid/tanh: v_exp + v_rcp (no IEEE divide sequence)
__device__ __forceinline__ float sigm(float x){
  return __builtin_amdgcn_rcpf(1.0f + __expf(-x));
}
__device__ __forceinline__ float tanhfast(float x){
  return 1.0f - 2.0f*__builtin_amdgcn_rcpf(1.0f + __expf(2.0f*x));
}

// ---------------- K0: Wih -> bf16; Whh -> fp8 e4m3 (x4 scale, compensated by h*0.25) ----------------
extern "C" __global__ __launch_bounds__(256) void k0_cvt(
    const float* __restrict__ whf, const float* __restrict__ whb,
    const float* __restrict__ wif, const float* __restrict__ wib,
    u32* __restrict__ whh8, u16* __restrict__ wih_bf)
{
  int i = blockIdx.x * 256 + threadIdx.x;   // 0..262143
  wih_bf[i]          = f2bf(wif[i]);
  wih_bf[262144 + i] = f2bf(wib[i]);
  if (i < 131072) {
    const float* src = (i < 65536) ? (whf + (size_t)i*4) : (whb + (size_t)(i - 65536)*4);
    float4 v = *(const float4*)src;
    int hi = __builtin_amdgcn_cvt_pk_fp8_f32(v.z*4.f, v.w*4.f, 0, true);
    int pk = __builtin_amdgcn_cvt_pk_fp8_f32(v.x*4.f, v.y*4.f, hi, false);
    whh8[i] = (u32)pk;
  }
}

// ---------------- K_init: lengths per batch row (single block) ----------------
extern "C" __global__ __launch_bounds__(256) void k_init(
    const int* __restrict__ mask, int* __restrict__ lenv)
{
  int tid = threadIdx.x;
  if (tid < 64) lenv[tid] = 0;
  __syncthreads();
  int r = tid >> 2, p = tid & 3;
  int s = 0;
  for (int k = 0; k < 128; ++k) s += mask[r*T_LEN + p*128 + k];
  atomicAdd(&lenv[r], s);
}

// ---------------- KG: gather emb[inp] and convert to bf16, layout [t*64+b][256] ----------------
extern "C" __global__ __launch_bounds__(256) void kg_emb(
    const int* __restrict__ inp, const float* __restrict__ emb, u16* __restrict__ xemb)
{
  int r = blockIdx.x*2 + (threadIdx.x >> 7);    // 0..32767
  int col = (threadIdx.x & 127) * 2;
  int b = r & 63, t = r >> 6;
  int tok = inp[b*T_LEN + t];
  float2 v = *(const float2*)(emb + (size_t)tok*256 + col);
  u32 pk = ((u32)f2bf(v.x)) | (((u32)f2bf(v.y)) << 16);
  *(u32*)(xemb + (size_t)r*256 + col) = pk;
}

// ---------------- K1: xW[(dir*4+rg)][t][row16][1024] = bf16( xemb @ Wih^T + b ) ----------------
// A = Wih (M=gates, AGPR-resident), B = xemb (N=16 rows). Lane holds row=lane&15,
// gates q*4+J consecutive -> 8B coalesced stores. grid (64 t-chunks, 32).
extern "C" __global__ __launch_bounds__(256, 1) void k1_proj(
    const u16* __restrict__ xemb, const u16* __restrict__ wih,
    const float* __restrict__ b_f, const float* __restrict__ b_b,
    u16* __restrict__ xW)
{
  int tc = blockIdx.x;              // t-chunk of 8
  int gb = blockIdx.y;              // 0..31
  int dir  = gb >> 4;
  int nblk = gb & 15;               // 64-gate block within dir
  int w    = threadIdx.x >> 6;      // wave id = row-group (rows 16w..16w+16)
  int lane = threadIdx.x & 63;
  int lr = lane & 15, q = lane >> 4;

  // A-operand weight fragments: 4 m-tiles x 8 K-frags = 128 regs, AGPR-pinned
  bf8 bw[4][8];
  const u16* wbase = wih + (size_t)dir*262144 + (size_t)nblk*64*256;
  #pragma unroll
  for (int n = 0; n < 4; ++n)
    #pragma unroll
    for (int kt = 0; kt < 8; ++kt)
      bw[n][kt] = *(const bf8*)(wbase + (size_t)(n*16 + lr)*256 + kt*32 + q*8);
  #pragma unroll
  for (int n = 0; n < 4; ++n) {
    asm volatile("" : "+a"(bw[n][0]), "+a"(bw[n][1]), "+a"(bw[n][2]), "+a"(bw[n][3]));
    asm volatile("" : "+a"(bw[n][4]), "+a"(bw[n][5]), "+a"(bw[n][6]), "+a"(bw[n][7]));
  }

  const float* bias = dir ? b_b : b_f;
  float4 bv[4];
  #pragma unroll
  for (int n = 0; n < 4; ++n) bv[n] = *(const float4*)(bias + nblk*64 + n*16 + q*4);

  for (int ti = 0; ti < 8; ++ti) {
    int t = tc*8 + ti;
    bf8 af[8];   // B-operand: xemb rows (n = lane&15)
    #pragma unroll
    for (int kt = 0; kt < 8; ++kt)
      af[kt] = *(const bf8*)(xemb + ((size_t)t*64 + w*16 + lr)*256 + kt*32 + q*8);

    f32x4 acc[4];
    #pragma unroll
    for (int n = 0; n < 4; ++n) { acc[n][0]=0.f; acc[n][1]=0.f; acc[n][2]=0.f; acc[n][3]=0.f; }
    #pragma unroll
    for (int kt = 0; kt < 8; ++kt)
      #pragma unroll
      for (int n = 0; n < 4; ++n)
        acc[n] = __builtin_amdgcn_mfma_f32_16x16x32_bf16(bw[n][kt], af[kt], acc[n], 0, 0, 0);

    u16* xp = xW + ((size_t)(dir*4 + w)*T_LEN + t)*16384 + (size_t)lr*1024;
    #pragma unroll
    for (int n = 0; n < 4; ++n) {
      ushort4 st;
      st.x = f2bf(acc[n][0] + bv[n].x);
      st.y = f2bf(acc[n][1] + bv[n].y);
      st.z = f2bf(acc[n][2] + bv[n].z);
      st.w = f2bf(acc[n][3] + bv[n].w);
      *(ushort4*)(xp + nblk*64 + n*16 + q*4) = st;
    }
  }
}

// ---------------- K2: LSTM recurrence, zero cross-block communication ----------------
// Block = (dir, 16-row group): 8 blocks x 512 thr (2 waves/SIMD). Whh fp8 AGPR-resident.
// A=W (M=gates), B=h (N=rows); xW folded into MFMA C-init; t+1 prefetch issued right
// after C-init. Barrier = raw `s_waitcnt lgkmcnt(0); s_barrier` — LDS-only semantics, so
// h_out stores and xW prefetch stay IN FLIGHT across the barrier (no vmcnt(0) drain).
// Gate math uses v_rcp_f32 (no IEEE divide sequence).
extern "C" __global__ __launch_bounds__(512, 2) void k2_lstm(
    const u32* __restrict__ whh8, const u16* __restrict__ xW,
    const int* __restrict__ lenv, u16* __restrict__ h_out)
{
  __shared__ __align__(16) unsigned char hb[2][16*264];

  int blk = blockIdx.x;             // 0..7
  int dir = blk >> 2;
  int rg  = blk & 3;
  int r0  = rg * 16;
  int w   = threadIdx.x >> 6;       // 0..7: chan slice (32 chans)
  int lane = threadIdx.x & 63;
  int lr = lane & 15, q = lane >> 4;
  int cw = w * 32;

  for (int i = threadIdx.x; i < 1056; i += 512)     // zero both h buffers (h(0)=0)
    ((unsigned long long*)hb)[i] = 0ull;

  // A-operand fp8 weight fragments: 4 gates x 2 chan-subtiles x 8 K-frags = 128 AGPRs
  i64 bw[4][2][8];
  const unsigned char* wb = (const unsigned char*)whh8 + (size_t)dir*262144;
  #pragma unroll
  for (int g = 0; g < 4; ++g)
    #pragma unroll
    for (int s2 = 0; s2 < 2; ++s2)
      #pragma unroll
      for (int kt = 0; kt < 8; ++kt)
        bw[g][s2][kt] = *(const i64*)(wb + (size_t)(g*256 + cw + 16*s2 + lr)*256 + kt*32 + q*8);
  #pragma unroll
  for (int g = 0; g < 4; ++g)
    #pragma unroll
    for (int s2 = 0; s2 < 2; ++s2) {
      asm volatile("" : "+a"(bw[g][s2][0]), "+a"(bw[g][s2][1]), "+a"(bw[g][s2][2]), "+a"(bw[g][s2][3]));
      asm volatile("" : "+a"(bw[g][s2][4]), "+a"(bw[g][s2][5]), "+a"(bw[g][s2][6]), "+a"(bw[g][s2][7]));
    }

  float cst[2][4] = {{0.f,0.f,0.f,0.f},{0.f,0.f,0.f,0.f}};
  float hst[2][4] = {{0.f,0.f,0.f,0.f},{0.f,0.f,0.f,0.f}};
  int lnr = lenv[r0 + lr];          // row mask is per-lane scalar

  const u16* xbase = xW + (size_t)(dir*4 + rg)*T_LEN*16384 + (size_t)lr*1024;
  int t0 = dir ? (T_LEN-1) : 0;
  ushort4 xv[4][2];
  {
    const u16* xp = xbase + (size_t)t0*16384;
    #pragma unroll
    for (int g = 0; g < 4; ++g)
      #pragma unroll
      for (int s2 = 0; s2 < 2; ++s2)
        xv[g][s2] = *(const ushort4*)(xp + g*256 + cw + 16*s2 + q*4);
  }
  __syncthreads();

  for (int s = 0; s < T_LEN; ++s) {
    int t = dir ? (T_LEN-1-s) : s;
    const unsigned char* hr = hb[s & 1];
    i64 af[8];                      // B-operand: h rows (n = lane&15)
    #pragma unroll
    for (int kt = 0; kt < 8; ++kt)
      af[kt] = *(const i64*)(hr + lr*264 + kt*32 + q*8);

    // C-init = xW contribution; xv dead after this
    f32x4 acc[2][4];
    #pragma unroll
    for (int s2 = 0; s2 < 2; ++s2)
      #pragma unroll
      for (int g = 0; g < 4; ++g)
        #pragma unroll
        for (int J = 0; J < 4; ++J)
          acc[s2][g][J] = bf2f(((const u16*)&xv[g][s2])[J]);

    if (s < T_LEN-1) {              // prefetch next xW NOW — stays in flight across barrier
      int tn = dir ? (T_LEN-2-s) : (s+1);
      const u16* xp = xbase + (size_t)tn*16384;
      #pragma unroll
      for (int g = 0; g < 4; ++g)
        #pragma unroll
        for (int s2 = 0; s2 < 2; ++s2)
          xv[g][s2] = *(const ushort4*)(xp + g*256 + cw + 16*s2 + q*4);
    }

    #pragma unroll
    for (int kt = 0; kt < 8; ++kt)
      #pragma unroll
      for (int s2 = 0; s2 < 2; ++s2)
        #pragma unroll
        for (int g = 0; g < 4; ++g)
          acc[s2][g] = __builtin_amdgcn_mfma_f32_16x16x32_fp8_fp8(bw[g][s2][kt], af[kt], acc[s2][g], 0, 0, 0);

    unsigned char* hw = hb[(s+1) & 1];
    u16* ho = h_out + ((size_t)(dir*T_LEN + t)*NB + r0 + lr)*256;
    bool mk = (t < lnr);
    #pragma unroll
    for (int s2 = 0; s2 < 2; ++s2) {
      ushort4 hv;
      #pragma unroll
      for (int J = 0; J < 4; ++J) {
        float ip = acc[s2][0][J];
        float fp = acc[s2][1][J];
        float gp = acc[s2][2][J];
        float op = acc[s2][3][J];
        float cn = sigm(fp)*cst[s2][J] + sigm(ip)*tanhfast(gp);
        float hn = sigm(op)*tanhfast(cn);
        cst[s2][J] = mk ? cn : cst[s2][J];
        hst[s2][J] = mk ? hn : hst[s2][J];
        ((u16*)&hv)[J] = f2bf(hst[s2][J]);
      }
      int lo = __builtin_amdgcn_cvt_pk_fp8_f32(hst[s2][0]*0.25f, hst[s2][1]*0.25f, 0, false);
      int pk = __builtin_amdgcn_cvt_pk_fp8_f32(hst[s2][2]*0.25f, hst[s2][3]*0.25f, lo, true);
      int ch = cw + 16*s2 + q*4;
      *(u32*)(hw + lr*264 + ch) = (u32)pk;       // 4B LDS write (fp8 x4)
      *(ushort4*)(ho + ch) = hv;                 // 8B global store (bf16 x4)
    }
    // LDS-only barrier: wait own LDS ops, then s_barrier. Global stores/loads uninvolved.
    asm volatile("s_waitcnt lgkmcnt(0)\n\ts_barrier" ::: "memory");
  }
}

// ---------------- K3: emissions em[t*64+b][32] = [h_f|h_b] @ W_tag^T + b_tag (fp32 out) ----------------
extern "C" __global__ __launch_bounds__(256, 2) void k3_emit(
    const u16* __restrict__ h_out, const float* __restrict__ W_tag,
    const float* __restrict__ b_tag, float* __restrict__ em)
{
  int wv = threadIdx.x >> 6, lane = threadIdx.x & 63;
  int lr = lane & 15, q = lane >> 4;
  size_t r0 = ((size_t)blockIdx.x*4 + wv) * 16;   // grid 512 -> 2048 row tiles (32768 rows)

  bf8 a[16];
  #pragma unroll
  for (int kt = 0; kt < 16; ++kt) {
    const u16* hp = h_out + (size_t)(kt>>3)*T_LEN*NB*256 + (r0 + lr)*256 + (kt&7)*32 + q*8;
    a[kt] = *(const bf8*)hp;
  }
  f32x4 acc[2];
  acc[0][0]=0.f;acc[0][1]=0.f;acc[0][2]=0.f;acc[0][3]=0.f; acc[1]=acc[0];
  #pragma unroll
  for (int n = 0; n < 2; ++n) {
    #pragma unroll
    for (int kt = 0; kt < 16; ++kt) {
      const float* wr = W_tag + (size_t)(n*16 + lr)*512 + kt*32 + q*8;
      bf8 bfr;
      #pragma unroll
      for (int e = 0; e < 8; ++e) bfr[e] = (short)f2bf(wr[e]);
      acc[n] = __builtin_amdgcn_mfma_f32_16x16x32_bf16(a[kt], bfr, acc[n], 0, 0, 0);
    }
  }
  #pragma unroll
  for (int n = 0; n < 2; ++n) {
    float bt = b_tag[n*16 + lr];
    #pragma unroll
    for (int J = 0; J < 4; ++J)
      em[(r0 + q*4 + J)*32 + n*16 + lr] = acc[n][J] + bt;
  }
}

// ---------------- K5: CRF forward scan + gold score; half-wave (32 lanes) per batch row ----------------
extern "C" __global__ __launch_bounds__(64) void k5_crf(
    const int* __restrict__ gold, const int* __restrict__ lenv,
    const float* __restrict__ em, const float* __restrict__ trans,
    float* __restrict__ out)
{
  __shared__ float trans_s[32][33];
  int tid = threadIdx.x;
  for (int i = tid; i < 1024; i += 64) trans_s[i>>5][i&31] = trans[i];
  __syncthreads();

  int half = tid >> 5;
  int j = tid & 31;                 // tag
  int b = blockIdx.x*2 + half;      // grid 32 -> b 0..63
  int len = lenv[b];
  float score = (j == STOPID) ? 0.f : -10000.f;
  float gscore = 0.f;
  int g_cur = gold[b*T_LEN];

  float e = em[(size_t)b*32 + j];   // t=0 emission (len >= 256 always)
  for (int t = 0; t < len; ++t) {
    float en = (t+1 < len) ? em[((size_t)(t+1)*64 + b)*32 + j] : 0.f;  // prefetch off critical path
    float m = -3.0e38f;
    #pragma unroll
    for (int p = 0; p < 32; ++p) {
      float sp = __shfl(score, p, 32);
      m = fmaxf(m, sp + trans_s[j][p]);
    }
    float se = 0.f;
    #pragma unroll
    for (int p = 0; p < 32; ++p) {
      float sp = __shfl(score, p, 32);
      se += __expf(sp + trans_s[j][p] - m);
    }
    score = e + m + __logf(se);
    if (t + 1 < T_LEN) {
      int g_next = gold[b*T_LEN + t + 1];
      float emg = __shfl(e, g_next, 32);
      gscore += emg + trans_s[g_next][g_cur];
      g_cur = g_next;
    }
    e = en;
  }
  float v = score + trans_s[STOPID][j];
  float m = v;
  #pragma unroll
  for (int off = 16; off; off >>= 1) m = fmaxf(m, __shfl_xor(m, off, 32));
  float se = __expf(v - m);
  #pragma unroll
  for (int off = 16; off; off >>= 1) se += __shfl_xor(se, off, 32);
  float Z = m + __logf(se);
  if (j == 0) {
    int g_last = gold[b*T_LEN + len - 1];
    out[b] = Z - (gscore + trans_s[STOPID][g_last]);
  }
}

extern "C" void kernel_launch(void* const* d_in, const int* in_sizes, int n_in,
                              void* d_out, int out_size, void* d_ws, size_t ws_size,
                              hipStream_t stream)
{
  const int*   inp   = (const int*)  d_in[0];
  const int*   gold  = (const int*)  d_in[1];
  const int*   mask  = (const int*)  d_in[2];
  const float* emb   = (const float*)d_in[3];
  const float* Wih_f = (const float*)d_in[4];
  const float* Whh_f = (const float*)d_in[5];
  const float* b_f   = (const float*)d_in[6];
  const float* Wih_b = (const float*)d_in[7];
  const float* Whh_b = (const float*)d_in[8];
  const float* b_b   = (const float*)d_in[9];
  const float* W_tag = (const float*)d_in[10];
  const float* b_tag = (const float*)d_in[11];
  const float* trans = (const float*)d_in[12];
  float* out = (float*)d_out;

  char* ws = (char*)d_ws;
  u32* whh8   = (u32*)(ws + 0);                 // 512 KiB fp8 Whh (both dirs)
  u16* wih_bf = (u16*)(ws + 1048576);           // 1 MiB bf16 Wih
  u16* xW     = (u16*)(ws + 2097152);           // 128 MiB [(dir,rg)][t][row16][1024]  (k1..k2)
  float* em   = (float*)(ws + 2097152);         // 4 MiB OVERLAY on xW                 (k3..k5)
  u16* h_outp = (u16*)(ws + 136314880);         // 32 MiB  [dir][t][row][256]          (k2..k3)
  u16* xemb   = (u16*)(ws + 136314880);         // 16 MiB OVERLAY on h_out             (kg..k1)
  int* lenv   = (int*)(ws + 169869312);         // 256 B

  hipLaunchKernelGGL(k0_cvt,  dim3(1024),     dim3(256), 0, stream,
                     Whh_f, Whh_b, Wih_f, Wih_b, whh8, wih_bf);
  hipLaunchKernelGGL(k_init,  dim3(1),        dim3(256), 0, stream, mask, lenv);
  hipLaunchKernelGGL(kg_emb,  dim3(16384),    dim3(256), 0, stream, inp, emb, xemb);
  hipLaunchKernelGGL(k1_proj, dim3(64, 32),   dim3(256), 0, stream,
                     xemb, wih_bf, b_f, b_b, xW);
  hipLaunchKernelGGL(k2_lstm, dim3(8),        dim3(512), 0, stream,
                     whh8, xW, lenv, h_outp);
  hipLaunchKernelGGL(k3_emit, dim3(512),      dim3(256), 0, stream,
                     h_outp, W_tag, b_tag, em);
  hipLaunchKernelGGL(k5_crf,  dim3(32),       dim3(64),  0, stream,
                     gold, lenv, em, trans, out);
}